// Round 11
// baseline (554.081 us; speedup 1.0000x reference)
//
#include <hip/hip_runtime.h>
#include <cstdint>
#include <cstddef>

// ---------------------------------------------------------------------------
// GraphPartitionModule: quantile-masked 3-way edge partition -> per-class
// normalized-Laplacian powers (D=2) -> theta combination -> MLP head.
//
// R11: quantile phase = 4 fused qhist launches (was 10 launches / 5 scans).
//  - qvnext ELIMINATED by threshold equivalence: masks only compare, and no
//    data lies strictly between consecutive order stats, so
//      thr_pos = v0;  thr_neg = (frac>0 && !dup) ? nextafter_up(v0) : v0
//    reproduce the reference masks exactly (v[k+1]'s value is never needed).
//  - qinit/qupdate/qfinal folded into qhist via last-block-done (device
//    atomic counter; hist re-read with atomicAdd(.,0) for coherence).
// Everything else = R10 (R6 gathers, R7 bucket CSR, R8 128-row MFMA GEMM).
// ---------------------------------------------------------------------------

#define WS_ALIGN(x) (((x) + 255) & ~(size_t)255)
#define NBLK 256          // edge-streaming blocks for count/scatter (must match)
#define MAXNB 1024        // LDS cap: supports nRows <= 512*1024
#define QHBLK 512         // qhist blocks

typedef __attribute__((ext_vector_type(8))) short short8;
typedef __attribute__((ext_vector_type(4))) float floatx4;

struct QState {
  unsigned n_neg, n_pos;
  unsigned prefix_neg, prefix_pos;
  int rank_neg, rank_pos;
  float frac_neg, frac_pos;
  float thr_neg, thr_pos;
  int dup_neg, dup_pos;
  unsigned barrier;
  unsigned hist_neg[256];
  unsigned hist_pos[256];
};

// monotone float<->uint key mapping (ascending float == ascending key)
__device__ __forceinline__ unsigned f2key(float v) {
  unsigned u = __float_as_uint(v);
  return (u & 0x80000000u) ? ~u : (u | 0x80000000u);
}
__device__ __forceinline__ float key2f(unsigned k) {
  unsigned u = (k & 0x80000000u) ? (k ^ 0x80000000u) : ~k;
  return __uint_as_float(u);
}

__device__ __forceinline__ unsigned short bf16rn(float x) {   // fp32 -> bf16 RNE
  unsigned u = __float_as_uint(x);
  u = (u + 0x7FFFu + ((u >> 16) & 1u)) >> 16;
  return (unsigned short)u;
}
__device__ __forceinline__ float bf2f(unsigned short v) {
  return __uint_as_float(((unsigned)v) << 16);
}

// ======== quantile radix-select: one fused kernel per round (R11) ===========
// Round r histograms the r-th byte of keys matching the current prefix; the
// last block to finish performs the bucket selection (and, for round 0, the
// rank computation; for round 3, the threshold computation), zeroes the hist,
// and resets the barrier for the next round.
__global__ __launch_bounds__(256) void qhist_kernel(const float* __restrict__ ep,
                                                    QState* st, int E, int round) {
  __shared__ unsigned hN[256], hP[256];
  __shared__ unsigned rN_[256], rP_[256];
  __shared__ unsigned isLast;
  int t = threadIdx.x;
  hN[t] = 0u; hP[t] = 0u;
  __syncthreads();
  int shift = 24 - 8 * round;
  unsigned maskHi = 0u;
  if (round > 0) maskHi = 0xFFFFFFFFu << (shift + 8);
  unsigned pN = st->prefix_neg & maskHi;
  unsigned pP = st->prefix_pos & maskHi;
  int stride = QHBLK * 256;
  for (int e = blockIdx.x * 256 + t; e < E; e += stride) {
    float v = ep[e];
    unsigned key = f2key(v);
    if (v <= 0.f) {
      if ((key & maskHi) == pN) atomicAdd(&hN[(key >> shift) & 255], 1u);
    } else {
      if ((key & maskHi) == pP) atomicAdd(&hP[(key >> shift) & 255], 1u);
    }
  }
  __syncthreads();
  unsigned cN = hN[t], cP = hP[t];
  if (cN) atomicAdd(&st->hist_neg[t], cN);
  if (cP) atomicAdd(&st->hist_pos[t], cP);
  __threadfence();
  if (t == 0) isLast = (atomicAdd(&st->barrier, 1u) == (unsigned)(QHBLK - 1)) ? 1u : 0u;
  __syncthreads();
  if (!isLast) return;
  __threadfence();
  // ---- last block: coherent re-read of the global hist ----
  unsigned hn = atomicAdd(&st->hist_neg[t], 0u);
  unsigned hp = atomicAdd(&st->hist_pos[t], 0u);
  hN[t] = hn; hP[t] = hp;
  if (round == 0) {
    rN_[t] = hn; rP_[t] = hp;
    __syncthreads();
    for (int off = 128; off > 0; off >>= 1) {
      if (t < off) { rN_[t] += rN_[t + off]; rP_[t] += rP_[t + off]; }
      __syncthreads();
    }
    if (t == 0) {
      unsigned nN = rN_[0], nP = rP_[0];
      st->n_neg = nN; st->n_pos = nP;
      float idxN = __fmul_rn(0.2f, (float)(nN - 1));
      float lowN = floorf(idxN);
      unsigned rn = (unsigned)(int)lowN;
      st->frac_neg = __fsub_rn(idxN, lowN);
      float idxP = __fmul_rn(0.8f, (float)(nP - 1));
      float lowP = floorf(idxP);
      unsigned rp = (unsigned)(int)lowP;
      st->frac_pos = __fsub_rn(idxP, lowP);
      {
        unsigned cum = 0, pref = 0;
        for (int b = 0; b < 256; ++b) {
          unsigned c = hN[b];
          if (rn < cum + c) { pref = ((unsigned)b) << 24; rn -= cum; break; }
          cum += c;
        }
        st->prefix_neg = pref; st->rank_neg = (int)rn;
      }
      {
        unsigned cum = 0, pref = 0;
        for (int b = 0; b < 256; ++b) {
          unsigned c = hP[b];
          if (rp < cum + c) { pref = ((unsigned)b) << 24; rp -= cum; break; }
          cum += c;
        }
        st->prefix_pos = pref; st->rank_pos = (int)rp;
      }
    }
  } else {
    __syncthreads();
    if (t == 0) {
      int dupN = 0, dupP = 0;
      unsigned prefN, prefP;
      {
        unsigned cum = 0; unsigned r = (unsigned)st->rank_neg; unsigned pref = st->prefix_neg;
        for (int b = 0; b < 256; ++b) {
          unsigned c = hN[b];
          if (r < cum + c) {
            pref |= ((unsigned)b) << shift; r -= cum;
            if (round == 3) dupN = (r + 1 < c) ? 1 : 0;
            break;
          }
          cum += c;
        }
        st->prefix_neg = pref; st->rank_neg = (int)r; prefN = pref;
      }
      {
        unsigned cum = 0; unsigned r = (unsigned)st->rank_pos; unsigned pref = st->prefix_pos;
        for (int b = 0; b < 256; ++b) {
          unsigned c = hP[b];
          if (r < cum + c) {
            pref |= ((unsigned)b) << shift; r -= cum;
            if (round == 3) dupP = (r + 1 < c) ? 1 : 0;
            break;
          }
          cum += c;
        }
        st->prefix_pos = pref; st->rank_pos = (int)r; prefP = pref;
      }
      if (round == 3) {
        st->dup_neg = dupN; st->dup_pos = dupP;
        // threshold equivalence (see header): pos uses v0; neg uses
        // nextafter-up(v0) iff frac>0 and v[k+1] > v[k].
        st->thr_pos = key2f(prefP);
        st->thr_neg = (st->frac_neg > 0.f && !dupN) ? key2f(prefN + 1u)
                                                    : key2f(prefN);
      }
    }
  }
  __syncthreads();
  // zero hist + reset barrier for next round
  st->hist_neg[t] = 0u;
  st->hist_pos[t] = 0u;
  if (t == 0) st->barrier = 0u;
}

// ======================= bucket-staged CSR build (R7-proven) ================
__global__ __launch_bounds__(256) void bucket_count(const float* __restrict__ ep,
    const int* __restrict__ dst, const QState* __restrict__ st,
    int* __restrict__ rowKey, int* __restrict__ part, int N, int E, int NB) {
  __shared__ unsigned hist[MAXNB];
  for (int i = threadIdx.x; i < NB; i += 256) hist[i] = 0u;
  __syncthreads();
  float thrN = st->thr_neg, thrP = st->thr_pos;
  const int stride = NBLK * 256;
  for (int e = blockIdx.x * 256 + threadIdx.x; e < E; e += stride) {
    float v = ep[e];
    int c = (v > thrP) ? 0 : ((v < thrN) ? 2 : 1);
    int row = c * N + dst[e];
    rowKey[e] = row;
    atomicAdd(&hist[row >> 9], 1u);
  }
  __syncthreads();
  for (int i = threadIdx.x; i < NB; i += 256)
    part[blockIdx.x * NB + i] = (int)hist[i];
}

__global__ __launch_bounds__(1024) void bucket_scanA(const int* __restrict__ part,
    int* __restrict__ bucketPtr, int NB) {
  __shared__ int s[1024];
  int t = threadIdx.x;
  int tot = 0;
  if (t < NB) {
#pragma unroll 4
    for (int blk = 0; blk < NBLK; ++blk) tot += part[blk * NB + t];
  }
  s[t] = tot;
  __syncthreads();
  for (int off = 1; off < 1024; off <<= 1) {
    int x = (t >= off) ? s[t - off] : 0;
    __syncthreads();
    s[t] += x;
    __syncthreads();
  }
  int excl = s[t] - tot;
  if (t < NB) bucketPtr[t] = excl;
  if (t == NB - 1) bucketPtr[NB] = excl + tot;
}

__global__ __launch_bounds__(64) void bucket_scanB(const int* __restrict__ part,
    const int* __restrict__ bucketPtr, int* __restrict__ baseArr, int NB) {
  int b = blockIdx.x;
  if (b >= NB) return;
  int l = threadIdx.x;                       // 0..63, 4 blocks each
  int p0 = part[(4 * l + 0) * NB + b];
  int p1 = part[(4 * l + 1) * NB + b];
  int p2 = part[(4 * l + 2) * NB + b];
  int p3 = part[(4 * l + 3) * NB + b];
  int mySum = p0 + p1 + p2 + p3;
  int v = mySum;
#pragma unroll
  for (int off = 1; off < 64; off <<= 1) {
    int x = __shfl_up(v, off);
    if (l >= off) v += x;
  }
  int base = bucketPtr[b] + (v - mySum);     // exclusive over blocks
  baseArr[(4 * l + 0) * NB + b] = base;
  baseArr[(4 * l + 1) * NB + b] = base + p0;
  baseArr[(4 * l + 2) * NB + b] = base + p0 + p1;
  baseArr[(4 * l + 3) * NB + b] = base + p0 + p1 + p2;
}

__global__ __launch_bounds__(256) void bucket_scatter(const int* __restrict__ rowKey,
    const int* __restrict__ src, const int* __restrict__ baseArr,
    int2* __restrict__ staged, int E, int NB) {
  __shared__ int cur[MAXNB];
  for (int i = threadIdx.x; i < NB; i += 256)
    cur[i] = baseArr[blockIdx.x * NB + i];
  __syncthreads();
  const int stride = NBLK * 256;
  for (int e = blockIdx.x * 256 + threadIdx.x; e < E; e += stride) {
    int row = rowKey[e];
    int pos = atomicAdd(&cur[row >> 9], 1);
    staged[pos] = make_int2(row, src[e]);
  }
}

__global__ __launch_bounds__(256) void bucket_build(const int2* __restrict__ staged,
    const int* __restrict__ bucketPtr, int* __restrict__ rowPtrG,
    float* __restrict__ dinv, int* __restrict__ eSrc, int nRows, int NB) {
  __shared__ int degL[512], excl2[512], cur[512], sb[256];
  int b = blockIdx.x;
  int lo = bucketPtr[b], hi = bucketPtr[b + 1];
  int rowBase = b << 9;
  int t = threadIdx.x;
  degL[t] = 0; degL[t + 256] = 0;
  __syncthreads();
  for (int e = lo + t; e < hi; e += 256)
    atomicAdd(&degL[staged[e].x - rowBase], 1);
  __syncthreads();
  int a0 = degL[2 * t], a1 = degL[2 * t + 1];
  sb[t] = a0 + a1;
  __syncthreads();
  for (int off = 1; off < 256; off <<= 1) {
    int x = (t >= off) ? sb[t - off] : 0;
    __syncthreads();
    sb[t] += x;
    __syncthreads();
  }
  int pairExcl = sb[t] - (a0 + a1);
  excl2[2 * t] = pairExcl;
  excl2[2 * t + 1] = pairExcl + a0;
  __syncthreads();
  for (int i = t; i < 512; i += 256) {
    int row = rowBase + i;
    if (row < nRows) {
      int base = lo + excl2[i];
      rowPtrG[row] = base;
      cur[i] = base;
      dinv[row] = 1.f / sqrtf(fmaxf((float)degL[i], 1.f));
    }
  }
  if (b == NB - 1 && t == 0) rowPtrG[nRows] = bucketPtr[NB];
  __syncthreads();
  for (int e = lo + t; e < hi; e += 256) {
    int2 p = staged[e];
    int pos = atomicAdd(&cur[p.x - rowBase], 1);
    eSrc[pos] = p.y;
  }
}

// ======================= propagation gathers (R6-proven form) ===============
// 16 lanes per row, ushort4 per lane, 4x unroll with two accumulator sets.
// STEP 1: f = h_bf [N,64] -> out L1_bf [3N,64]
// STEP 2: f = L1_bf [3N,64] -> out combo_bf [N,192] column block c
template<int STEP>
__global__ __launch_bounds__(256) void gather3_kernel(const unsigned short* __restrict__ f,
    const unsigned short* __restrict__ hb, unsigned short* __restrict__ outBuf,
    const int* __restrict__ rowPtr, const int* __restrict__ eSrc,
    const float* __restrict__ dinv, int N, int nRows) {
  int r = blockIdx.x * 16 + (threadIdx.x >> 4);
  if (r >= nRows) return;
  int l = threadIdx.x & 15;
  int c = r / N;
  int n = r - c * N;
  int beg = rowPtr[r], end = rowPtr[r + 1];
  const int cb = c * N;
  const int srcOfs = (STEP == 1) ? 0 : cb;   // L1_bf rows are class-offset
  float ax = 0.f, ay = 0.f, az = 0.f, aw = 0.f;
  float bx = 0.f, by = 0.f, bz = 0.f, bw = 0.f;
  int e = beg;
  for (; e + 4 <= end; e += 4) {
    int s0 = eSrc[e],     s1 = eSrc[e + 1];
    int s2 = eSrc[e + 2], s3 = eSrc[e + 3];
    float c0 = dinv[cb + s0], c1 = dinv[cb + s1];
    float c2 = dinv[cb + s2], c3 = dinv[cb + s3];
    ushort4 v0 = *(const ushort4*)&f[(size_t)(srcOfs + s0) * 64 + l * 4];
    ushort4 v1 = *(const ushort4*)&f[(size_t)(srcOfs + s1) * 64 + l * 4];
    ushort4 v2 = *(const ushort4*)&f[(size_t)(srcOfs + s2) * 64 + l * 4];
    ushort4 v3 = *(const ushort4*)&f[(size_t)(srcOfs + s3) * 64 + l * 4];
    ax += bf2f(v0.x) * c0; ay += bf2f(v0.y) * c0; az += bf2f(v0.z) * c0; aw += bf2f(v0.w) * c0;
    bx += bf2f(v1.x) * c1; by += bf2f(v1.y) * c1; bz += bf2f(v1.z) * c1; bw += bf2f(v1.w) * c1;
    ax += bf2f(v2.x) * c2; ay += bf2f(v2.y) * c2; az += bf2f(v2.z) * c2; aw += bf2f(v2.w) * c2;
    bx += bf2f(v3.x) * c3; by += bf2f(v3.y) * c3; bz += bf2f(v3.z) * c3; bw += bf2f(v3.w) * c3;
  }
  for (; e < end; ++e) {
    int s = eSrc[e];
    float sc = dinv[cb + s];
    ushort4 v = *(const ushort4*)&f[(size_t)(srcOfs + s) * 64 + l * 4];
    ax += bf2f(v.x) * sc; ay += bf2f(v.y) * sc;
    az += bf2f(v.z) * sc; aw += bf2f(v.w) * sc;
  }
  ax += bx; ay += by; az += bz; aw += bw;
  float di = dinv[r];
  if (STEP == 1) {
    ushort4 fv = *(const ushort4*)&f[(size_t)n * 64 + l * 4];
    ushort4 o;
    o.x = bf16rn(bf2f(fv.x) - di * ax);
    o.y = bf16rn(bf2f(fv.y) - di * ay);
    o.z = bf16rn(bf2f(fv.z) - di * az);
    o.w = bf16rn(bf2f(fv.w) - di * aw);
    *(ushort4*)&outBuf[(size_t)r * 64 + l * 4] = o;
  } else {
    const float chA[3] = {0.f, 0.f, 3.f};
    const float c1A[3] = {0.f, 3.f, -3.f};
    const float c2A[3] = {0.75f, -1.5f, 0.75f};
    float ch = chA[c], c1 = c1A[c], c2 = c2A[c];
    ushort4 fv = *(const ushort4*)&f[(size_t)r * 64 + l * 4];
    ushort4 hv = *(const ushort4*)&hb[(size_t)n * 64 + l * 4];
    float fx = bf2f(fv.x), fy = bf2f(fv.y), fz = bf2f(fv.z), fw = bf2f(fv.w);
    ushort4 o;
    o.x = bf16rn(ch * bf2f(hv.x) + c1 * fx + c2 * (fx - di * ax));
    o.y = bf16rn(ch * bf2f(hv.y) + c1 * fy + c2 * (fy - di * ay));
    o.z = bf16rn(ch * bf2f(hv.z) + c1 * fz + c2 * (fz - di * az));
    o.w = bf16rn(ch * bf2f(hv.w) + c1 * fw + c2 * (fw - di * aw));
    *(ushort4*)&outBuf[(size_t)n * 192 + c * 64 + l * 4] = o;
  }
}

// Per-class gather (fallback path), bf16 data, 4x unroll
template<int STEP>
__global__ __launch_bounds__(256) void gatherF_kernel(const unsigned short* __restrict__ f,
    const unsigned short* __restrict__ hb, unsigned short* __restrict__ outBuf,
    const int* __restrict__ rowPtr, const int* __restrict__ eSrc,
    const float* __restrict__ dinv, float ch, float c1, float c2, int N) {
  int n = blockIdx.x * 16 + (threadIdx.x >> 4);
  if (n >= N) return;
  int l = threadIdx.x & 15;
  int beg = rowPtr[n], end = rowPtr[n + 1];
  float ax = 0.f, ay = 0.f, az = 0.f, aw = 0.f;
  float bx = 0.f, by = 0.f, bz = 0.f, bw = 0.f;
  int e = beg;
  for (; e + 4 <= end; e += 4) {
    int s0 = eSrc[e], s1 = eSrc[e + 1], s2 = eSrc[e + 2], s3 = eSrc[e + 3];
    float c0 = dinv[s0], c1_ = dinv[s1], c2_ = dinv[s2], c3 = dinv[s3];
    ushort4 v0 = *(const ushort4*)&f[(size_t)s0 * 64 + l * 4];
    ushort4 v1 = *(const ushort4*)&f[(size_t)s1 * 64 + l * 4];
    ushort4 v2 = *(const ushort4*)&f[(size_t)s2 * 64 + l * 4];
    ushort4 v3 = *(const ushort4*)&f[(size_t)s3 * 64 + l * 4];
    ax += bf2f(v0.x) * c0; ay += bf2f(v0.y) * c0; az += bf2f(v0.z) * c0; aw += bf2f(v0.w) * c0;
    bx += bf2f(v1.x) * c1_; by += bf2f(v1.y) * c1_; bz += bf2f(v1.z) * c1_; bw += bf2f(v1.w) * c1_;
    ax += bf2f(v2.x) * c2_; ay += bf2f(v2.y) * c2_; az += bf2f(v2.z) * c2_; aw += bf2f(v2.w) * c2_;
    bx += bf2f(v3.x) * c3; by += bf2f(v3.y) * c3; bz += bf2f(v3.z) * c3; bw += bf2f(v3.w) * c3;
  }
  for (; e < end; ++e) {
    int s = eSrc[e];
    float sc = dinv[s];
    ushort4 v = *(const ushort4*)&f[(size_t)s * 64 + l * 4];
    ax += bf2f(v.x) * sc; ay += bf2f(v.y) * sc;
    az += bf2f(v.z) * sc; aw += bf2f(v.w) * sc;
  }
  ax += bx; ay += by; az += bz; aw += bw;
  float di = dinv[n];
  size_t idx = (size_t)n * 64 + l * 4;
  ushort4 fv = *(const ushort4*)&f[idx];
  float fx = bf2f(fv.x), fy = bf2f(fv.y), fz = bf2f(fv.z), fw = bf2f(fv.w);
  ushort4 o;
  if (STEP == 1) {
    o.x = bf16rn(fx - di * ax); o.y = bf16rn(fy - di * ay);
    o.z = bf16rn(fz - di * az); o.w = bf16rn(fw - di * aw);
  } else {
    ushort4 hv = *(const ushort4*)&hb[idx];
    o.x = bf16rn(ch * bf2f(hv.x) + c1 * fx + c2 * (fx - di * ax));
    o.y = bf16rn(ch * bf2f(hv.y) + c1 * fy + c2 * (fy - di * ay));
    o.z = bf16rn(ch * bf2f(hv.z) + c1 * fz + c2 * (fz - di * az));
    o.w = bf16rn(ch * bf2f(hv.w) + c1 * fw + c2 * (fw - di * aw));
  }
  *(ushort4*)&outBuf[idx] = o;
}

// ======================= MFMA GEMMs (R8: 128-row tiles) =====================
__global__ void wconvAll_kernel(const float* __restrict__ W1, const float* __restrict__ W2,
                                const float* __restrict__ W3,
                                unsigned short* __restrict__ Wt1,
                                unsigned short* __restrict__ Wt2,
                                unsigned short* __restrict__ Wt3) {
  int i = blockIdx.x * 256 + threadIdx.x;
  if (i < 8192) {                    // Wt1: 64 cols x K=128
    int col = i >> 7, k = i & 127;
    Wt1[i] = bf16rn(W1[(size_t)k * 64 + col]);
  } else if (i < 12288) {            // Wt2: 64 x 64
    int j = i - 8192;
    int col = j >> 6, k = j & 63;
    Wt2[j] = bf16rn(W2[(size_t)k * 64 + col]);
  } else if (i < 24576) {            // Wt3: 64 cols x K=192
    int j = i - 12288;
    int col = j / 192, k = j - col * 192;
    Wt3[j] = bf16rn(W3[(size_t)k * 64 + col]);
  }
}

// C[N,64] = A[N,K] @ Wt^T (bf16), fp32 accum via MFMA 16x16x32.
// 128-row x 64-col tile, 4 waves; wave w covers rows [w*32, w*32+32) via two
// A-fragments; 8 MFMAs between each barrier pair.
template<int K, int ABF, int OBF>
__global__ __launch_bounds__(256) void gemm_mfma_kernel(const void* __restrict__ Ain,
    const unsigned short* __restrict__ Wt, const float* __restrict__ bias,
    void* __restrict__ Cout, int N, int accum, int finish) {
  __shared__ short As[128 * 40];
  const int tid = threadIdx.x;
  const int wave = tid >> 6, lane = tid & 63;
  const int m = lane & 15, quad = lane >> 4;
  const int rowBase = blockIdx.x * 128;
  floatx4 acc[2][4] = {};
  const int rs = tid >> 1;          // staging row 0..127
  const int cs = (tid & 1) * 16;    // staging col base 0/16
  const int rowS = rowBase + rs;
  const int aRow0 = (wave * 32 + m) * 40 + quad * 8;
  const int aRow1 = aRow0 + 16 * 40;
  for (int kc = 0; kc < K; kc += 32) {
    short8 s0 = {0,0,0,0,0,0,0,0}, s1 = s0;
    if (rowS < N) {
      if (ABF) {
        const unsigned short* p = (const unsigned short*)Ain + (size_t)rowS * K + kc + cs;
        s0 = *(const short8*)p;
        s1 = *(const short8*)(p + 8);
      } else {
        const float* p = (const float*)Ain + (size_t)rowS * K + kc + cs;
        float4 v0 = *(const float4*)p;
        float4 v1 = *(const float4*)(p + 4);
        float4 v2 = *(const float4*)(p + 8);
        float4 v3 = *(const float4*)(p + 12);
        s0[0] = bf16rn(v0.x); s0[1] = bf16rn(v0.y); s0[2] = bf16rn(v0.z); s0[3] = bf16rn(v0.w);
        s0[4] = bf16rn(v1.x); s0[5] = bf16rn(v1.y); s0[6] = bf16rn(v1.z); s0[7] = bf16rn(v1.w);
        s1[0] = bf16rn(v2.x); s1[1] = bf16rn(v2.y); s1[2] = bf16rn(v2.z); s1[3] = bf16rn(v2.w);
        s1[4] = bf16rn(v3.x); s1[5] = bf16rn(v3.y); s1[6] = bf16rn(v3.z); s1[7] = bf16rn(v3.w);
      }
    }
    *(short8*)&As[rs * 40 + cs] = s0;
    *(short8*)&As[rs * 40 + cs + 8] = s1;
    __syncthreads();
    short8 af0 = *(const short8*)&As[aRow0];
    short8 af1 = *(const short8*)&As[aRow1];
    const unsigned short* wp = Wt + (size_t)m * K + kc + quad * 8;
#pragma unroll
    for (int ct = 0; ct < 4; ++ct) {
      short8 bf = *(const short8*)(wp + (size_t)ct * 16 * K);
      acc[0][ct] = __builtin_amdgcn_mfma_f32_16x16x32_bf16(af0, bf, acc[0][ct], 0, 0, 0);
      acc[1][ct] = __builtin_amdgcn_mfma_f32_16x16x32_bf16(af1, bf, acc[1][ct], 0, 0, 0);
    }
    __syncthreads();
  }
#pragma unroll
  for (int h = 0; h < 2; ++h) {
    const int r0 = rowBase + wave * 32 + h * 16 + quad * 4;
#pragma unroll
    for (int ct = 0; ct < 4; ++ct) {
      float b = finish ? bias[ct * 16 + m] : 0.f;
#pragma unroll
      for (int reg = 0; reg < 4; ++reg) {
        int row = r0 + reg;
        if (row < N) {
          float o = acc[h][ct][reg];
          if (OBF) {
            if (finish) o = fmaxf(o + b, 0.f);
            ((unsigned short*)Cout)[(size_t)row * 64 + ct * 16 + m] = bf16rn(o);
          } else {
            float* cp = (float*)Cout + (size_t)row * 64 + ct * 16 + m;
            if (accum) o += *cp;
            if (finish) o = fmaxf(o + b, 0.f);
            *cp = o;
          }
        }
      }
    }
  }
}

extern "C" void kernel_launch(void* const* d_in, const int* in_sizes, int n_in,
                              void* d_out, int out_size, void* d_ws, size_t ws_size,
                              hipStream_t stream) {
  const float* feat = (const float*)d_in[0];
  const float* ep   = (const float*)d_in[1];
  const int*   src  = (const int*)d_in[2];
  const int*   dst  = (const int*)d_in[3];
  const float* W1   = (const float*)d_in[4];
  const float* b1   = (const float*)d_in[5];
  const float* W2   = (const float*)d_in[6];
  const float* b2   = (const float*)d_in[7];
  const float* W3   = (const float*)d_in[8];
  const float* b3   = (const float*)d_in[9];
  float* out = (float*)d_out;
  const int N = in_sizes[0] / 128;
  const int E = in_sizes[1];
  const int nRows = 3 * N;
  const int NB = (nRows + 511) >> 9;   // 512-row buckets; requires NB <= MAXNB

  char* w = (char*)d_ws;
  size_t off = 0;
  QState* st = (QState*)(w + off);           off += WS_ALIGN(sizeof(QState));
  const size_t zeroBytes = off;              // QState only (hist + barrier)
  int* rowPtr = (int*)(w + off);             off += WS_ALIGN((size_t)(nRows + 1) * 4);
  float* dinv = (float*)(w + off);           off += WS_ALIGN((size_t)nRows * 4);
  int* rowKey = (int*)(w + off);             off += WS_ALIGN((size_t)E * 4);
  int* partHist = (int*)(w + off);           off += WS_ALIGN((size_t)NBLK * NB * 4);
  int* baseArr = (int*)(w + off);            off += WS_ALIGN((size_t)NBLK * NB * 4);
  int* bucketPtr = (int*)(w + off);          off += WS_ALIGN((size_t)(NB + 1) * 4);
  int2* staged = (int2*)(w + off);           off += WS_ALIGN((size_t)E * 8);
  int* eSrc = (int*)(w + off);               off += WS_ALIGN((size_t)E * 4);
  unsigned short* Wt1 = (unsigned short*)(w + off); off += WS_ALIGN((size_t)64 * 128 * 2);
  unsigned short* Wt2 = (unsigned short*)(w + off); off += WS_ALIGN((size_t)64 * 64 * 2);
  unsigned short* Wt3 = (unsigned short*)(w + off); off += WS_ALIGN((size_t)64 * 192 * 2);
  unsigned short* h_bf = (unsigned short*)(w + off); off += WS_ALIGN((size_t)N * 64 * 2);
  // fused: L1_bf [3N,64] + combo_bf [N,192]; fallback: L1 [N,64] + combo [N,64]
  const size_t fusedNeed = off + (size_t)nRows * 64 * 2 + (size_t)N * 192 * 2;
  const bool fused = (ws_size >= fusedNeed);
  unsigned short* L1_bf = (unsigned short*)(w + off);   // also temp for h1
  unsigned short* combo_bf = fused
      ? (unsigned short*)(w + off + WS_ALIGN((size_t)nRows * 64 * 2))
      : (unsigned short*)(w + off + WS_ALIGN((size_t)N * 64 * 2));
  (void)n_in; (void)out_size;

  hipMemsetAsync(d_ws, 0, zeroBytes, stream);

  // ---- quantile thresholds: 4 fused radix rounds ----
  for (int r = 0; r < 4; ++r)
    qhist_kernel<<<QHBLK, 256, 0, stream>>>(ep, st, E, r);

  // ---- weights + MLP (independent of edges) ----
  wconvAll_kernel<<<(24576 + 255) / 256, 256, 0, stream>>>(W1, W2, W3, Wt1, Wt2, Wt3);
  const int gb = (N + 127) / 128;
  gemm_mfma_kernel<128, 0, 1><<<gb, 256, 0, stream>>>(feat, Wt1, b1, L1_bf, N, 0, 1);
  gemm_mfma_kernel<64, 1, 1><<<gb, 256, 0, stream>>>(L1_bf, Wt2, b2, h_bf, N, 0, 1);

  // ---- bucket-staged CSR build ----
  bucket_count<<<NBLK, 256, 0, stream>>>(ep, dst, st, rowKey, partHist, N, E, NB);
  bucket_scanA<<<1, 1024, 0, stream>>>(partHist, bucketPtr, NB);
  bucket_scanB<<<NB, 64, 0, stream>>>(partHist, bucketPtr, baseArr, NB);
  bucket_scatter<<<NBLK, 256, 0, stream>>>(rowKey, src, baseArr, staged, E, NB);
  bucket_build<<<NB, 256, 0, stream>>>(staged, bucketPtr, rowPtr, dinv, eSrc, nRows, NB);

  // ---- propagation + head ----
  if (fused) {
    const int g3 = (nRows + 15) / 16;
    gather3_kernel<1><<<g3, 256, 0, stream>>>(h_bf, h_bf, L1_bf, rowPtr, eSrc, dinv, N, nRows);
    gather3_kernel<2><<<g3, 256, 0, stream>>>(L1_bf, h_bf, combo_bf, rowPtr, eSrc, dinv, N, nRows);
    gemm_mfma_kernel<192, 1, 0><<<gb, 256, 0, stream>>>(combo_bf, Wt3, b3, out, N, 0, 1);
  } else {
    const float chArr[3] = {0.f, 0.f, 3.f};
    const float c1Arr[3] = {0.f, 3.f, -3.f};
    const float c2Arr[3] = {0.75f, -1.5f, 0.75f};
    const int ggrid = (N + 15) / 16;
    for (int c = 0; c < 3; ++c) {
      const int* rp = rowPtr + (size_t)c * N;
      const float* dv = dinv + (size_t)c * N;
      gatherF_kernel<1><<<ggrid, 256, 0, stream>>>(h_bf, nullptr, L1_bf, rp, eSrc, dv,
                                                   0.f, 0.f, 0.f, N);
      gatherF_kernel<2><<<ggrid, 256, 0, stream>>>(L1_bf, h_bf, combo_bf, rp, eSrc, dv,
                                                   chArr[c], c1Arr[c], c2Arr[c], N);
      gemm_mfma_kernel<64, 1, 0><<<gb, 256, 0, stream>>>(combo_bf, Wt2, b3, out,
                                                         N, c > 0 ? 1 : 0, c == 2 ? 1 : 0);
    }
  }
}

// Round 12
// 470.905 us; speedup vs baseline: 1.1766x; 1.1766x over previous
//
#include <hip/hip_runtime.h>
#include <cstdint>
#include <cstddef>

// ---------------------------------------------------------------------------
// GraphPartitionModule: quantile-masked 3-way edge partition -> per-class
// normalized-Laplacian powers (D=2) -> theta combination -> MLP head.
//
// R12: R10 structure (separate quantile launches, NO device fences — R11's
// last-block fusion cost ~65us/round in cross-XCD fence traffic) + R11's
// validated threshold equivalence:
//   thr_pos = v0;  thr_neg = (frac>0 && !dup) ? nextafter_up(v0) : v0
// which deletes the qvnext full scan and qfinal (round-3 qupdate computes
// thresholds directly). Quantile = 4 scans + 3 tiny launches.
// Keeps: R6 gathers, R7 bucket CSR, R8 128-row MFMA GEMM.
// ---------------------------------------------------------------------------

#define WS_ALIGN(x) (((x) + 255) & ~(size_t)255)
#define NBLK 256          // edge-streaming blocks for count/scatter (must match)
#define MAXNB 1024        // LDS cap: supports nRows <= 512*1024

typedef __attribute__((ext_vector_type(8))) short short8;
typedef __attribute__((ext_vector_type(4))) float floatx4;

struct QState {
  unsigned n_neg, n_pos;
  unsigned prefix_neg, prefix_pos;
  int rank_neg, rank_pos;
  float frac_neg, frac_pos;
  float thr_neg, thr_pos;
  unsigned hist_neg[256];
  unsigned hist_pos[256];
};

// monotone float<->uint key mapping (ascending float == ascending key)
__device__ __forceinline__ unsigned f2key(float v) {
  unsigned u = __float_as_uint(v);
  return (u & 0x80000000u) ? ~u : (u | 0x80000000u);
}
__device__ __forceinline__ float key2f(unsigned k) {
  unsigned u = (k & 0x80000000u) ? (k ^ 0x80000000u) : ~k;
  return __uint_as_float(u);
}

__device__ __forceinline__ unsigned short bf16rn(float x) {   // fp32 -> bf16 RNE
  unsigned u = __float_as_uint(x);
  u = (u + 0x7FFFu + ((u >> 16) & 1u)) >> 16;
  return (unsigned short)u;
}
__device__ __forceinline__ float bf2f(unsigned short v) {
  return __uint_as_float(((unsigned)v) << 16);
}

// ======================= quantile radix-select (R10-proven scans) ===========
__global__ __launch_bounds__(256) void qhist_kernel(const float* __restrict__ ep,
                                                    QState* st, int E, int round) {
  __shared__ unsigned hN[256], hP[256];
  hN[threadIdx.x] = 0u; hP[threadIdx.x] = 0u;
  __syncthreads();
  int shift = 24 - 8 * round;
  unsigned maskHi = 0u;
  if (round > 0) maskHi = 0xFFFFFFFFu << (shift + 8);
  unsigned pN = st->prefix_neg & maskHi;
  unsigned pP = st->prefix_pos & maskHi;
  int stride = gridDim.x * blockDim.x;
  for (int e = blockIdx.x * blockDim.x + threadIdx.x; e < E; e += stride) {
    float v = ep[e];
    unsigned key = f2key(v);
    if (v <= 0.f) {
      if ((key & maskHi) == pN) atomicAdd(&hN[(key >> shift) & 255], 1u);
    } else {
      if ((key & maskHi) == pP) atomicAdd(&hP[(key >> shift) & 255], 1u);
    }
  }
  __syncthreads();
  unsigned cN = hN[threadIdx.x], cP = hP[threadIdx.x];
  if (cN) atomicAdd(&st->hist_neg[threadIdx.x], cN);
  if (cP) atomicAdd(&st->hist_pos[threadIdx.x], cP);
}

// After round-0 hist: counts -> ranks (f32 nanquantile semantics) + round-0
// bucket select; re-zero hists.
__global__ __launch_bounds__(256) void qinit_kernel(QState* st) {
  __shared__ unsigned sN[256], sP[256], rN_[256], rP_[256];
  int t = threadIdx.x;
  unsigned hn = st->hist_neg[t], hp = st->hist_pos[t];
  sN[t] = hn; sP[t] = hp; rN_[t] = hn; rP_[t] = hp;
  __syncthreads();
  for (int off = 128; off > 0; off >>= 1) {
    if (t < off) { rN_[t] += rN_[t + off]; rP_[t] += rP_[t + off]; }
    __syncthreads();
  }
  if (t == 0) {
    unsigned nN = rN_[0], nP = rP_[0];
    st->n_neg = nN; st->n_pos = nP;
    float idxN = __fmul_rn(0.2f, (float)(nN - 1));
    float lowN = floorf(idxN);
    unsigned rn = (unsigned)(int)lowN;
    st->frac_neg = __fsub_rn(idxN, lowN);
    float idxP = __fmul_rn(0.8f, (float)(nP - 1));
    float lowP = floorf(idxP);
    unsigned rp = (unsigned)(int)lowP;
    st->frac_pos = __fsub_rn(idxP, lowP);
    {
      unsigned cum = 0, pref = 0;
      for (int b = 0; b < 256; ++b) {
        unsigned c = sN[b];
        if (rn < cum + c) { pref = ((unsigned)b) << 24; rn -= cum; break; }
        cum += c;
      }
      st->prefix_neg = pref; st->rank_neg = (int)rn;
    }
    {
      unsigned cum = 0, pref = 0;
      for (int b = 0; b < 256; ++b) {
        unsigned c = sP[b];
        if (rp < cum + c) { pref = ((unsigned)b) << 24; rp -= cum; break; }
        cum += c;
      }
      st->prefix_pos = pref; st->rank_pos = (int)rp;
    }
  }
  st->hist_neg[t] = 0u; st->hist_pos[t] = 0u;
}

// Bucket select for rounds 1-3; round 3 computes the thresholds directly
// via the R11-validated equivalence (no qvnext/qfinal needed).
__global__ void qupdate_kernel(QState* st, int round) {
  int shift = 24 - 8 * round;
  int dupN = 0, dupP = 0;
  unsigned prefN, prefP;
  {
    unsigned cum = 0; unsigned r = (unsigned)st->rank_neg; unsigned pref = st->prefix_neg;
    for (int b = 0; b < 256; ++b) {
      unsigned c = st->hist_neg[b];
      if (r < cum + c) {
        pref |= ((unsigned)b) << shift; r -= cum;
        if (round == 3) dupN = (r + 1 < c) ? 1 : 0;
        break;
      }
      cum += c;
    }
    st->prefix_neg = pref; st->rank_neg = (int)r; prefN = pref;
  }
  {
    unsigned cum = 0; unsigned r = (unsigned)st->rank_pos; unsigned pref = st->prefix_pos;
    for (int b = 0; b < 256; ++b) {
      unsigned c = st->hist_pos[b];
      if (r < cum + c) {
        pref |= ((unsigned)b) << shift; r -= cum;
        if (round == 3) dupP = (r + 1 < c) ? 1 : 0;
        break;
      }
      cum += c;
    }
    st->prefix_pos = pref; st->rank_pos = (int)r; prefP = pref;
  }
  if (round == 3) {
    // masks only compare; nothing lies strictly between order stats:
    //   pos mask (ep > thr): thr = v0 is exact in all cases.
    //   neg mask (ep < thr): thr = nextafter_up(v0) iff frac>0 and v1>v0.
    st->thr_pos = key2f(prefP);
    st->thr_neg = (st->frac_neg > 0.f && !dupN) ? key2f(prefN + 1u)
                                                : key2f(prefN);
    (void)dupP;
  }
  for (int i = 0; i < 256; ++i) { st->hist_neg[i] = 0u; st->hist_pos[i] = 0u; }
}

// ======================= bucket-staged CSR build (R7-proven) ================
__global__ __launch_bounds__(256) void bucket_count(const float* __restrict__ ep,
    const int* __restrict__ dst, const QState* __restrict__ st,
    int* __restrict__ rowKey, int* __restrict__ part, int N, int E, int NB) {
  __shared__ unsigned hist[MAXNB];
  for (int i = threadIdx.x; i < NB; i += 256) hist[i] = 0u;
  __syncthreads();
  float thrN = st->thr_neg, thrP = st->thr_pos;
  const int stride = NBLK * 256;
  for (int e = blockIdx.x * 256 + threadIdx.x; e < E; e += stride) {
    float v = ep[e];
    int c = (v > thrP) ? 0 : ((v < thrN) ? 2 : 1);
    int row = c * N + dst[e];
    rowKey[e] = row;
    atomicAdd(&hist[row >> 9], 1u);
  }
  __syncthreads();
  for (int i = threadIdx.x; i < NB; i += 256)
    part[blockIdx.x * NB + i] = (int)hist[i];
}

__global__ __launch_bounds__(1024) void bucket_scanA(const int* __restrict__ part,
    int* __restrict__ bucketPtr, int NB) {
  __shared__ int s[1024];
  int t = threadIdx.x;
  int tot = 0;
  if (t < NB) {
#pragma unroll 4
    for (int blk = 0; blk < NBLK; ++blk) tot += part[blk * NB + t];
  }
  s[t] = tot;
  __syncthreads();
  for (int off = 1; off < 1024; off <<= 1) {
    int x = (t >= off) ? s[t - off] : 0;
    __syncthreads();
    s[t] += x;
    __syncthreads();
  }
  int excl = s[t] - tot;
  if (t < NB) bucketPtr[t] = excl;
  if (t == NB - 1) bucketPtr[NB] = excl + tot;
}

__global__ __launch_bounds__(64) void bucket_scanB(const int* __restrict__ part,
    const int* __restrict__ bucketPtr, int* __restrict__ baseArr, int NB) {
  int b = blockIdx.x;
  if (b >= NB) return;
  int l = threadIdx.x;                       // 0..63, 4 blocks each
  int p0 = part[(4 * l + 0) * NB + b];
  int p1 = part[(4 * l + 1) * NB + b];
  int p2 = part[(4 * l + 2) * NB + b];
  int p3 = part[(4 * l + 3) * NB + b];
  int mySum = p0 + p1 + p2 + p3;
  int v = mySum;
#pragma unroll
  for (int off = 1; off < 64; off <<= 1) {
    int x = __shfl_up(v, off);
    if (l >= off) v += x;
  }
  int base = bucketPtr[b] + (v - mySum);     // exclusive over blocks
  baseArr[(4 * l + 0) * NB + b] = base;
  baseArr[(4 * l + 1) * NB + b] = base + p0;
  baseArr[(4 * l + 2) * NB + b] = base + p0 + p1;
  baseArr[(4 * l + 3) * NB + b] = base + p0 + p1 + p2;
}

__global__ __launch_bounds__(256) void bucket_scatter(const int* __restrict__ rowKey,
    const int* __restrict__ src, const int* __restrict__ baseArr,
    int2* __restrict__ staged, int E, int NB) {
  __shared__ int cur[MAXNB];
  for (int i = threadIdx.x; i < NB; i += 256)
    cur[i] = baseArr[blockIdx.x * NB + i];
  __syncthreads();
  const int stride = NBLK * 256;
  for (int e = blockIdx.x * 256 + threadIdx.x; e < E; e += stride) {
    int row = rowKey[e];
    int pos = atomicAdd(&cur[row >> 9], 1);
    staged[pos] = make_int2(row, src[e]);
  }
}

__global__ __launch_bounds__(256) void bucket_build(const int2* __restrict__ staged,
    const int* __restrict__ bucketPtr, int* __restrict__ rowPtrG,
    float* __restrict__ dinv, int* __restrict__ eSrc, int nRows, int NB) {
  __shared__ int degL[512], excl2[512], cur[512], sb[256];
  int b = blockIdx.x;
  int lo = bucketPtr[b], hi = bucketPtr[b + 1];
  int rowBase = b << 9;
  int t = threadIdx.x;
  degL[t] = 0; degL[t + 256] = 0;
  __syncthreads();
  for (int e = lo + t; e < hi; e += 256)
    atomicAdd(&degL[staged[e].x - rowBase], 1);
  __syncthreads();
  int a0 = degL[2 * t], a1 = degL[2 * t + 1];
  sb[t] = a0 + a1;
  __syncthreads();
  for (int off = 1; off < 256; off <<= 1) {
    int x = (t >= off) ? sb[t - off] : 0;
    __syncthreads();
    sb[t] += x;
    __syncthreads();
  }
  int pairExcl = sb[t] - (a0 + a1);
  excl2[2 * t] = pairExcl;
  excl2[2 * t + 1] = pairExcl + a0;
  __syncthreads();
  for (int i = t; i < 512; i += 256) {
    int row = rowBase + i;
    if (row < nRows) {
      int base = lo + excl2[i];
      rowPtrG[row] = base;
      cur[i] = base;
      dinv[row] = 1.f / sqrtf(fmaxf((float)degL[i], 1.f));
    }
  }
  if (b == NB - 1 && t == 0) rowPtrG[nRows] = bucketPtr[NB];
  __syncthreads();
  for (int e = lo + t; e < hi; e += 256) {
    int2 p = staged[e];
    int pos = atomicAdd(&cur[p.x - rowBase], 1);
    eSrc[pos] = p.y;
  }
}

// ======================= propagation gathers (R6-proven form) ===============
// 16 lanes per row, ushort4 per lane, 4x unroll with two accumulator sets.
// STEP 1: f = h_bf [N,64] -> out L1_bf [3N,64]
// STEP 2: f = L1_bf [3N,64] -> out combo_bf [N,192] column block c
template<int STEP>
__global__ __launch_bounds__(256) void gather3_kernel(const unsigned short* __restrict__ f,
    const unsigned short* __restrict__ hb, unsigned short* __restrict__ outBuf,
    const int* __restrict__ rowPtr, const int* __restrict__ eSrc,
    const float* __restrict__ dinv, int N, int nRows) {
  int r = blockIdx.x * 16 + (threadIdx.x >> 4);
  if (r >= nRows) return;
  int l = threadIdx.x & 15;
  int c = r / N;
  int n = r - c * N;
  int beg = rowPtr[r], end = rowPtr[r + 1];
  const int cb = c * N;
  const int srcOfs = (STEP == 1) ? 0 : cb;   // L1_bf rows are class-offset
  float ax = 0.f, ay = 0.f, az = 0.f, aw = 0.f;
  float bx = 0.f, by = 0.f, bz = 0.f, bw = 0.f;
  int e = beg;
  for (; e + 4 <= end; e += 4) {
    int s0 = eSrc[e],     s1 = eSrc[e + 1];
    int s2 = eSrc[e + 2], s3 = eSrc[e + 3];
    float c0 = dinv[cb + s0], c1 = dinv[cb + s1];
    float c2 = dinv[cb + s2], c3 = dinv[cb + s3];
    ushort4 v0 = *(const ushort4*)&f[(size_t)(srcOfs + s0) * 64 + l * 4];
    ushort4 v1 = *(const ushort4*)&f[(size_t)(srcOfs + s1) * 64 + l * 4];
    ushort4 v2 = *(const ushort4*)&f[(size_t)(srcOfs + s2) * 64 + l * 4];
    ushort4 v3 = *(const ushort4*)&f[(size_t)(srcOfs + s3) * 64 + l * 4];
    ax += bf2f(v0.x) * c0; ay += bf2f(v0.y) * c0; az += bf2f(v0.z) * c0; aw += bf2f(v0.w) * c0;
    bx += bf2f(v1.x) * c1; by += bf2f(v1.y) * c1; bz += bf2f(v1.z) * c1; bw += bf2f(v1.w) * c1;
    ax += bf2f(v2.x) * c2; ay += bf2f(v2.y) * c2; az += bf2f(v2.z) * c2; aw += bf2f(v2.w) * c2;
    bx += bf2f(v3.x) * c3; by += bf2f(v3.y) * c3; bz += bf2f(v3.z) * c3; bw += bf2f(v3.w) * c3;
  }
  for (; e < end; ++e) {
    int s = eSrc[e];
    float sc = dinv[cb + s];
    ushort4 v = *(const ushort4*)&f[(size_t)(srcOfs + s) * 64 + l * 4];
    ax += bf2f(v.x) * sc; ay += bf2f(v.y) * sc;
    az += bf2f(v.z) * sc; aw += bf2f(v.w) * sc;
  }
  ax += bx; ay += by; az += bz; aw += bw;
  float di = dinv[r];
  if (STEP == 1) {
    ushort4 fv = *(const ushort4*)&f[(size_t)n * 64 + l * 4];
    ushort4 o;
    o.x = bf16rn(bf2f(fv.x) - di * ax);
    o.y = bf16rn(bf2f(fv.y) - di * ay);
    o.z = bf16rn(bf2f(fv.z) - di * az);
    o.w = bf16rn(bf2f(fv.w) - di * aw);
    *(ushort4*)&outBuf[(size_t)r * 64 + l * 4] = o;
  } else {
    const float chA[3] = {0.f, 0.f, 3.f};
    const float c1A[3] = {0.f, 3.f, -3.f};
    const float c2A[3] = {0.75f, -1.5f, 0.75f};
    float ch = chA[c], c1 = c1A[c], c2 = c2A[c];
    ushort4 fv = *(const ushort4*)&f[(size_t)r * 64 + l * 4];
    ushort4 hv = *(const ushort4*)&hb[(size_t)n * 64 + l * 4];
    float fx = bf2f(fv.x), fy = bf2f(fv.y), fz = bf2f(fv.z), fw = bf2f(fv.w);
    ushort4 o;
    o.x = bf16rn(ch * bf2f(hv.x) + c1 * fx + c2 * (fx - di * ax));
    o.y = bf16rn(ch * bf2f(hv.y) + c1 * fy + c2 * (fy - di * ay));
    o.z = bf16rn(ch * bf2f(hv.z) + c1 * fz + c2 * (fz - di * az));
    o.w = bf16rn(ch * bf2f(hv.w) + c1 * fw + c2 * (fw - di * aw));
    *(ushort4*)&outBuf[(size_t)n * 192 + c * 64 + l * 4] = o;
  }
}

// Per-class gather (fallback path), bf16 data, 4x unroll
template<int STEP>
__global__ __launch_bounds__(256) void gatherF_kernel(const unsigned short* __restrict__ f,
    const unsigned short* __restrict__ hb, unsigned short* __restrict__ outBuf,
    const int* __restrict__ rowPtr, const int* __restrict__ eSrc,
    const float* __restrict__ dinv, float ch, float c1, float c2, int N) {
  int n = blockIdx.x * 16 + (threadIdx.x >> 4);
  if (n >= N) return;
  int l = threadIdx.x & 15;
  int beg = rowPtr[n], end = rowPtr[n + 1];
  float ax = 0.f, ay = 0.f, az = 0.f, aw = 0.f;
  float bx = 0.f, by = 0.f, bz = 0.f, bw = 0.f;
  int e = beg;
  for (; e + 4 <= end; e += 4) {
    int s0 = eSrc[e], s1 = eSrc[e + 1], s2 = eSrc[e + 2], s3 = eSrc[e + 3];
    float c0 = dinv[s0], c1_ = dinv[s1], c2_ = dinv[s2], c3 = dinv[s3];
    ushort4 v0 = *(const ushort4*)&f[(size_t)s0 * 64 + l * 4];
    ushort4 v1 = *(const ushort4*)&f[(size_t)s1 * 64 + l * 4];
    ushort4 v2 = *(const ushort4*)&f[(size_t)s2 * 64 + l * 4];
    ushort4 v3 = *(const ushort4*)&f[(size_t)s3 * 64 + l * 4];
    ax += bf2f(v0.x) * c0; ay += bf2f(v0.y) * c0; az += bf2f(v0.z) * c0; aw += bf2f(v0.w) * c0;
    bx += bf2f(v1.x) * c1_; by += bf2f(v1.y) * c1_; bz += bf2f(v1.z) * c1_; bw += bf2f(v1.w) * c1_;
    ax += bf2f(v2.x) * c2_; ay += bf2f(v2.y) * c2_; az += bf2f(v2.z) * c2_; aw += bf2f(v2.w) * c2_;
    bx += bf2f(v3.x) * c3; by += bf2f(v3.y) * c3; bz += bf2f(v3.z) * c3; bw += bf2f(v3.w) * c3;
  }
  for (; e < end; ++e) {
    int s = eSrc[e];
    float sc = dinv[s];
    ushort4 v = *(const ushort4*)&f[(size_t)s * 64 + l * 4];
    ax += bf2f(v.x) * sc; ay += bf2f(v.y) * sc;
    az += bf2f(v.z) * sc; aw += bf2f(v.w) * sc;
  }
  ax += bx; ay += by; az += bz; aw += bw;
  float di = dinv[n];
  size_t idx = (size_t)n * 64 + l * 4;
  ushort4 fv = *(const ushort4*)&f[idx];
  float fx = bf2f(fv.x), fy = bf2f(fv.y), fz = bf2f(fv.z), fw = bf2f(fv.w);
  ushort4 o;
  if (STEP == 1) {
    o.x = bf16rn(fx - di * ax); o.y = bf16rn(fy - di * ay);
    o.z = bf16rn(fz - di * az); o.w = bf16rn(fw - di * aw);
  } else {
    ushort4 hv = *(const ushort4*)&hb[idx];
    o.x = bf16rn(ch * bf2f(hv.x) + c1 * fx + c2 * (fx - di * ax));
    o.y = bf16rn(ch * bf2f(hv.y) + c1 * fy + c2 * (fy - di * ay));
    o.z = bf16rn(ch * bf2f(hv.z) + c1 * fz + c2 * (fz - di * az));
    o.w = bf16rn(ch * bf2f(hv.w) + c1 * fw + c2 * (fw - di * aw));
  }
  *(ushort4*)&outBuf[idx] = o;
}

// ======================= MFMA GEMMs (R8: 128-row tiles) =====================
__global__ void wconvAll_kernel(const float* __restrict__ W1, const float* __restrict__ W2,
                                const float* __restrict__ W3,
                                unsigned short* __restrict__ Wt1,
                                unsigned short* __restrict__ Wt2,
                                unsigned short* __restrict__ Wt3) {
  int i = blockIdx.x * 256 + threadIdx.x;
  if (i < 8192) {                    // Wt1: 64 cols x K=128
    int col = i >> 7, k = i & 127;
    Wt1[i] = bf16rn(W1[(size_t)k * 64 + col]);
  } else if (i < 12288) {            // Wt2: 64 x 64
    int j = i - 8192;
    int col = j >> 6, k = j & 63;
    Wt2[j] = bf16rn(W2[(size_t)k * 64 + col]);
  } else if (i < 24576) {            // Wt3: 64 cols x K=192
    int j = i - 12288;
    int col = j / 192, k = j - col * 192;
    Wt3[j] = bf16rn(W3[(size_t)k * 64 + col]);
  }
}

// C[N,64] = A[N,K] @ Wt^T (bf16), fp32 accum via MFMA 16x16x32.
// 128-row x 64-col tile, 4 waves; wave w covers rows [w*32, w*32+32) via two
// A-fragments; 8 MFMAs between each barrier pair.
template<int K, int ABF, int OBF>
__global__ __launch_bounds__(256) void gemm_mfma_kernel(const void* __restrict__ Ain,
    const unsigned short* __restrict__ Wt, const float* __restrict__ bias,
    void* __restrict__ Cout, int N, int accum, int finish) {
  __shared__ short As[128 * 40];
  const int tid = threadIdx.x;
  const int wave = tid >> 6, lane = tid & 63;
  const int m = lane & 15, quad = lane >> 4;
  const int rowBase = blockIdx.x * 128;
  floatx4 acc[2][4] = {};
  const int rs = tid >> 1;          // staging row 0..127
  const int cs = (tid & 1) * 16;    // staging col base 0/16
  const int rowS = rowBase + rs;
  const int aRow0 = (wave * 32 + m) * 40 + quad * 8;
  const int aRow1 = aRow0 + 16 * 40;
  for (int kc = 0; kc < K; kc += 32) {
    short8 s0 = {0,0,0,0,0,0,0,0}, s1 = s0;
    if (rowS < N) {
      if (ABF) {
        const unsigned short* p = (const unsigned short*)Ain + (size_t)rowS * K + kc + cs;
        s0 = *(const short8*)p;
        s1 = *(const short8*)(p + 8);
      } else {
        const float* p = (const float*)Ain + (size_t)rowS * K + kc + cs;
        float4 v0 = *(const float4*)p;
        float4 v1 = *(const float4*)(p + 4);
        float4 v2 = *(const float4*)(p + 8);
        float4 v3 = *(const float4*)(p + 12);
        s0[0] = bf16rn(v0.x); s0[1] = bf16rn(v0.y); s0[2] = bf16rn(v0.z); s0[3] = bf16rn(v0.w);
        s0[4] = bf16rn(v1.x); s0[5] = bf16rn(v1.y); s0[6] = bf16rn(v1.z); s0[7] = bf16rn(v1.w);
        s1[0] = bf16rn(v2.x); s1[1] = bf16rn(v2.y); s1[2] = bf16rn(v2.z); s1[3] = bf16rn(v2.w);
        s1[4] = bf16rn(v3.x); s1[5] = bf16rn(v3.y); s1[6] = bf16rn(v3.z); s1[7] = bf16rn(v3.w);
      }
    }
    *(short8*)&As[rs * 40 + cs] = s0;
    *(short8*)&As[rs * 40 + cs + 8] = s1;
    __syncthreads();
    short8 af0 = *(const short8*)&As[aRow0];
    short8 af1 = *(const short8*)&As[aRow1];
    const unsigned short* wp = Wt + (size_t)m * K + kc + quad * 8;
#pragma unroll
    for (int ct = 0; ct < 4; ++ct) {
      short8 bf = *(const short8*)(wp + (size_t)ct * 16 * K);
      acc[0][ct] = __builtin_amdgcn_mfma_f32_16x16x32_bf16(af0, bf, acc[0][ct], 0, 0, 0);
      acc[1][ct] = __builtin_amdgcn_mfma_f32_16x16x32_bf16(af1, bf, acc[1][ct], 0, 0, 0);
    }
    __syncthreads();
  }
#pragma unroll
  for (int h = 0; h < 2; ++h) {
    const int r0 = rowBase + wave * 32 + h * 16 + quad * 4;
#pragma unroll
    for (int ct = 0; ct < 4; ++ct) {
      float b = finish ? bias[ct * 16 + m] : 0.f;
#pragma unroll
      for (int reg = 0; reg < 4; ++reg) {
        int row = r0 + reg;
        if (row < N) {
          float o = acc[h][ct][reg];
          if (OBF) {
            if (finish) o = fmaxf(o + b, 0.f);
            ((unsigned short*)Cout)[(size_t)row * 64 + ct * 16 + m] = bf16rn(o);
          } else {
            float* cp = (float*)Cout + (size_t)row * 64 + ct * 16 + m;
            if (accum) o += *cp;
            if (finish) o = fmaxf(o + b, 0.f);
            *cp = o;
          }
        }
      }
    }
  }
}

extern "C" void kernel_launch(void* const* d_in, const int* in_sizes, int n_in,
                              void* d_out, int out_size, void* d_ws, size_t ws_size,
                              hipStream_t stream) {
  const float* feat = (const float*)d_in[0];
  const float* ep   = (const float*)d_in[1];
  const int*   src  = (const int*)d_in[2];
  const int*   dst  = (const int*)d_in[3];
  const float* W1   = (const float*)d_in[4];
  const float* b1   = (const float*)d_in[5];
  const float* W2   = (const float*)d_in[6];
  const float* b2   = (const float*)d_in[7];
  const float* W3   = (const float*)d_in[8];
  const float* b3   = (const float*)d_in[9];
  float* out = (float*)d_out;
  const int N = in_sizes[0] / 128;
  const int E = in_sizes[1];
  const int nRows = 3 * N;
  const int NB = (nRows + 511) >> 9;   // 512-row buckets; requires NB <= MAXNB

  char* w = (char*)d_ws;
  size_t off = 0;
  QState* st = (QState*)(w + off);           off += WS_ALIGN(sizeof(QState));
  const size_t zeroBytes = off;              // QState only
  int* rowPtr = (int*)(w + off);             off += WS_ALIGN((size_t)(nRows + 1) * 4);
  float* dinv = (float*)(w + off);           off += WS_ALIGN((size_t)nRows * 4);
  int* rowKey = (int*)(w + off);             off += WS_ALIGN((size_t)E * 4);
  int* partHist = (int*)(w + off);           off += WS_ALIGN((size_t)NBLK * NB * 4);
  int* baseArr = (int*)(w + off);            off += WS_ALIGN((size_t)NBLK * NB * 4);
  int* bucketPtr = (int*)(w + off);          off += WS_ALIGN((size_t)(NB + 1) * 4);
  int2* staged = (int2*)(w + off);           off += WS_ALIGN((size_t)E * 8);
  int* eSrc = (int*)(w + off);               off += WS_ALIGN((size_t)E * 4);
  unsigned short* Wt1 = (unsigned short*)(w + off); off += WS_ALIGN((size_t)64 * 128 * 2);
  unsigned short* Wt2 = (unsigned short*)(w + off); off += WS_ALIGN((size_t)64 * 64 * 2);
  unsigned short* Wt3 = (unsigned short*)(w + off); off += WS_ALIGN((size_t)64 * 192 * 2);
  unsigned short* h_bf = (unsigned short*)(w + off); off += WS_ALIGN((size_t)N * 64 * 2);
  // fused: L1_bf [3N,64] + combo_bf [N,192]; fallback: L1 [N,64] + combo [N,64]
  const size_t fusedNeed = off + (size_t)nRows * 64 * 2 + (size_t)N * 192 * 2;
  const bool fused = (ws_size >= fusedNeed);
  unsigned short* L1_bf = (unsigned short*)(w + off);   // also temp for h1
  unsigned short* combo_bf = fused
      ? (unsigned short*)(w + off + WS_ALIGN((size_t)nRows * 64 * 2))
      : (unsigned short*)(w + off + WS_ALIGN((size_t)N * 64 * 2));
  (void)n_in; (void)out_size;

  hipMemsetAsync(d_ws, 0, zeroBytes, stream);

  // ---- quantile thresholds (exact radix-select, 4 scans, no qvnext) ----
  qhist_kernel<<<512, 256, 0, stream>>>(ep, st, E, 0);
  qinit_kernel<<<1, 256, 0, stream>>>(st);
  for (int r = 1; r < 4; ++r) {
    qhist_kernel<<<512, 256, 0, stream>>>(ep, st, E, r);
    qupdate_kernel<<<1, 1, 0, stream>>>(st, r);
  }

  // ---- weights + MLP (independent of edges) ----
  wconvAll_kernel<<<(24576 + 255) / 256, 256, 0, stream>>>(W1, W2, W3, Wt1, Wt2, Wt3);
  const int gb = (N + 127) / 128;
  gemm_mfma_kernel<128, 0, 1><<<gb, 256, 0, stream>>>(feat, Wt1, b1, L1_bf, N, 0, 1);
  gemm_mfma_kernel<64, 1, 1><<<gb, 256, 0, stream>>>(L1_bf, Wt2, b2, h_bf, N, 0, 1);

  // ---- bucket-staged CSR build ----
  bucket_count<<<NBLK, 256, 0, stream>>>(ep, dst, st, rowKey, partHist, N, E, NB);
  bucket_scanA<<<1, 1024, 0, stream>>>(partHist, bucketPtr, NB);
  bucket_scanB<<<NB, 64, 0, stream>>>(partHist, bucketPtr, baseArr, NB);
  bucket_scatter<<<NBLK, 256, 0, stream>>>(rowKey, src, baseArr, staged, E, NB);
  bucket_build<<<NB, 256, 0, stream>>>(staged, bucketPtr, rowPtr, dinv, eSrc, nRows, NB);

  // ---- propagation + head ----
  if (fused) {
    const int g3 = (nRows + 15) / 16;
    gather3_kernel<1><<<g3, 256, 0, stream>>>(h_bf, h_bf, L1_bf, rowPtr, eSrc, dinv, N, nRows);
    gather3_kernel<2><<<g3, 256, 0, stream>>>(L1_bf, h_bf, combo_bf, rowPtr, eSrc, dinv, N, nRows);
    gemm_mfma_kernel<192, 1, 0><<<gb, 256, 0, stream>>>(combo_bf, Wt3, b3, out, N, 0, 1);
  } else {
    const float chArr[3] = {0.f, 0.f, 3.f};
    const float c1Arr[3] = {0.f, 3.f, -3.f};
    const float c2Arr[3] = {0.75f, -1.5f, 0.75f};
    const int ggrid = (N + 15) / 16;
    for (int c = 0; c < 3; ++c) {
      const int* rp = rowPtr + (size_t)c * N;
      const float* dv = dinv + (size_t)c * N;
      gatherF_kernel<1><<<ggrid, 256, 0, stream>>>(h_bf, nullptr, L1_bf, rp, eSrc, dv,
                                                   0.f, 0.f, 0.f, N);
      gatherF_kernel<2><<<ggrid, 256, 0, stream>>>(L1_bf, h_bf, combo_bf, rp, eSrc, dv,
                                                   chArr[c], c1Arr[c], c2Arr[c], N);
      gemm_mfma_kernel<64, 1, 0><<<gb, 256, 0, stream>>>(combo_bf, Wt2, b3, out,
                                                         N, c > 0 ? 1 : 0, c == 2 ? 1 : 0);
    }
  }
}